// Round 6
// baseline (113.239 us; speedup 1.0000x reference)
//
#include <hip/hip_runtime.h>

typedef short s16x8 __attribute__((ext_vector_type(8)));
typedef float f32x4 __attribute__((ext_vector_type(4)));

constexpr int F  = 24;
constexpr int NP = 276;   // F*(F-1)/2
constexpr int E  = 64;
constexpr int CH = 4;     // pairs per block (276 = 69 * 4)
constexpr int NB = 64;    // batches per block
constexpr int OS = 260;   // out-buffer row stride in floats (260 % 32 == 4)

__device__ __forceinline__ unsigned short f2bf(float f) {
    unsigned int u = __builtin_bit_cast(unsigned int, f);
    return (unsigned short)((u + 0x7FFFu + ((u >> 16) & 1u)) >> 16);  // RNE
}

__global__ __launch_bounds__(256)
void bilinear_kernel(const float* __restrict__ x, const float* __restrict__ W,
                     float* __restrict__ out)
{
    __shared__ unsigned int BtU[2048];    // 8 KB: W[p]^T bf16, XOR-swizzled
    __shared__ float Obuf[NB * OS];       // 65 KB: 64 batches x 4 pairs x 64 f

    // ---- XCD swizzle: 4416 = 8 XCD x 552; per XCD: 8 batch-blocks x 69 chunks
    // (same batch window per XCD -> 3 MB x-slice L2-resident; W streams)
    const int bid = blockIdx.x;
    const int xcd = bid & 7;
    const int l   = bid >> 3;             // 0..551
    const int bb  = xcd * 8 + l / 69;     // batch-block 0..63
    const int ch  = l % 69;               // pair-chunk 0..68
    const int b0  = bb * NB;
    const int p0  = ch * CH;

    const int tid  = threadIdx.x;
    const int wv   = tid >> 6;
    const int ln   = tid & 63;
    const int lrow = ln & 15;
    const int lq   = ln >> 4;

    #pragma unroll 1
    for (int pp = 0; pp < CH; ++pp) {
        const int p = p0 + pp;

        // decode pair (i, j)
        int i = 0, rem = p;
        while (rem >= F - 1 - i) { rem -= F - 1 - i; ++i; }
        const int j = i + 1 + rem;

        if (pp) __syncthreads();   // prior waves done reading W buffer

        // ---- stage W[p]^T into LDS as bf16, XOR-swizzled (proven R4 code) ----
        const float* Wp = W + (size_t)p * E * E;
        #pragma unroll
        for (int it = 0; it < 8; ++it) {
            int q  = tid + it * 256;
            int f  = q & 63;
            int e2 = q >> 6;
            float w0 = Wp[(2 * e2) * E + f];
            float w1 = Wp[(2 * e2 + 1) * E + f];
            unsigned int pk = (unsigned int)f2bf(w0) | ((unsigned int)f2bf(w1) << 16);
            BtU[f * 32 + (e2 ^ ((f & 7) << 2))] = pk;
        }
        __syncthreads();

        const unsigned short* Bts = reinterpret_cast<const unsigned short*>(BtU);

        // B fragments (W^T) for this pair
        s16x8 bfrag[4][2];
        #pragma unroll
        for (int n = 0; n < 4; ++n) {
            int fc = n * 16 + lrow;
            #pragma unroll
            for (int kk = 0; kk < 2; ++kk) {
                int k0 = kk * 32 + lq * 8;
                int sidx = fc * 64 + (k0 ^ ((fc & 7) << 3));
                bfrag[n][kk] = *reinterpret_cast<const s16x8*>(&Bts[sidx]);
            }
        }

        // A fragments: wave wv owns batches b0 + wv*16 .. +15
        const int bA = b0 + wv * 16 + lrow;
        const float* xi_ = x + ((size_t)bA * F + i) * E;
        s16x8 afrag[2];
        #pragma unroll
        for (int kk = 0; kk < 2; ++kk) {
            int k0 = kk * 32 + lq * 8;
            float4 lo = *reinterpret_cast<const float4*>(xi_ + k0);
            float4 hi = *reinterpret_cast<const float4*>(xi_ + k0 + 4);
            s16x8 a;
            a[0] = (short)f2bf(lo.x); a[1] = (short)f2bf(lo.y);
            a[2] = (short)f2bf(lo.z); a[3] = (short)f2bf(lo.w);
            a[4] = (short)f2bf(hi.x); a[5] = (short)f2bf(hi.y);
            a[6] = (short)f2bf(hi.z); a[7] = (short)f2bf(hi.w);
            afrag[kk] = a;
        }

        f32x4 acc[4];
        #pragma unroll
        for (int n = 0; n < 4; ++n) {
            acc[n] = (f32x4){0.f, 0.f, 0.f, 0.f};
            acc[n] = __builtin_amdgcn_mfma_f32_16x16x32_bf16(afrag[0], bfrag[n][0], acc[n], 0, 0, 0);
            acc[n] = __builtin_amdgcn_mfma_f32_16x16x32_bf16(afrag[1], bfrag[n][1], acc[n], 0, 0, 0);
        }

        // ---- epilogue: * xj, scatter into LDS out-buffer ----
        // acc[n][r] = D[b_loc = wv*16 + lq*4 + r][f = n*16 + lrow]
        // Obuf bank = (16*lq + 4*r + 16*n + lrow) % 32 -> 2-way max (free)
        #pragma unroll
        for (int n = 0; n < 4; ++n) {
            int fc = n * 16 + lrow;
            #pragma unroll
            for (int r = 0; r < 4; ++r) {
                int row = wv * 16 + lq * 4 + r;
                float xj = x[((size_t)(b0 + row) * F + j) * E + fc];
                Obuf[row * OS + pp * 64 + fc] = acc[n][r] * xj;
            }
        }
        // Obuf cells are thread-exclusive; rows wave-private -> no barrier
    }

    // ---- flush: wave wv writes its own 16 rows, 1 KB contiguous each ----
    #pragma unroll
    for (int rr = 0; rr < 16; ++rr) {
        const int row = wv * 16 + rr;
        const f32x4 v = *reinterpret_cast<const f32x4*>(&Obuf[row * OS + ln * 4]);
        float* op = out + ((size_t)(b0 + row) * NP + p0) * E + ln * 4;
        *reinterpret_cast<f32x4*>(op) = v;
    }
}

extern "C" void kernel_launch(void* const* d_in, const int* in_sizes, int n_in,
                              void* d_out, int out_size, void* d_ws, size_t ws_size,
                              hipStream_t stream)
{
    const float* x = (const float*)d_in[0];
    const float* W = (const float*)d_in[1];
    float* out = (float*)d_out;
    dim3 grid(64 * 69, 1, 1);   // 4416 = 8 XCDs x (8 batch-blocks x 69 chunks)
    bilinear_kernel<<<grid, 256, 0, stream>>>(x, W, out);
}

// Round 7
// 89.745 us; speedup vs baseline: 1.2618x; 1.2618x over previous
//
#include <hip/hip_runtime.h>

typedef short s16x8 __attribute__((ext_vector_type(8)));
typedef float f32x4 __attribute__((ext_vector_type(4)));

constexpr int F  = 24;
constexpr int NP = 276;   // F*(F-1)/2
constexpr int E  = 64;

__device__ __forceinline__ unsigned short f2bf(float f) {
    unsigned int u = __builtin_bit_cast(unsigned int, f);
    return (unsigned short)((u + 0x7FFFu + ((u >> 16) & 1u)) >> 16);  // RNE
}

__device__ __forceinline__ s16x8 cvt8(float4 lo, float4 hi) {
    s16x8 a;
    a[0] = (short)f2bf(lo.x); a[1] = (short)f2bf(lo.y);
    a[2] = (short)f2bf(lo.z); a[3] = (short)f2bf(lo.w);
    a[4] = (short)f2bf(hi.x); a[5] = (short)f2bf(hi.y);
    a[6] = (short)f2bf(hi.z); a[7] = (short)f2bf(hi.w);
    return a;
}

__global__ __launch_bounds__(256)
void bilinear_kernel(const float* __restrict__ x, const float* __restrict__ W,
                     float* __restrict__ out)
{
    __shared__ unsigned int BtU[2048];   // 8 KB: W[p]^T bf16, XOR-swizzled

    // ---- XCD-aware swizzle (T1, as R4) ----
    const int bid = blockIdx.x;
    const int xcd = bid & 7;
    const int idx = bid >> 3;              // 0..551
    const int wl  = (idx >= NP) ? 1 : 0;
    const int p   = idx - wl * NP;
    const int b0  = (xcd * 2 + wl) * 256;

    const int tid  = threadIdx.x;
    const int wv   = tid >> 6;
    const int ln   = tid & 63;
    const int lrow = ln & 15;
    const int lq   = ln >> 4;

    // decode pair (i, j)
    int i = 0, rem = p;
    while (rem >= F - 1 - i) { rem -= F - 1 - i; ++i; }
    const int j = i + 1 + rem;

    // issue all loads for subtile s (A raw + xj) into the given buffers
    auto issue = [&](int s, float4 (&rA)[4], float (&rJ)[16]) {
        const int bA = b0 + s * 64 + wv * 16 + lrow;
        const float* xi_ = x + ((size_t)bA * F + i) * E;
        rA[0] = *reinterpret_cast<const float4*>(xi_ + lq * 8);
        rA[1] = *reinterpret_cast<const float4*>(xi_ + lq * 8 + 4);
        rA[2] = *reinterpret_cast<const float4*>(xi_ + 32 + lq * 8);
        rA[3] = *reinterpret_cast<const float4*>(xi_ + 32 + lq * 8 + 4);
        const int bj0 = b0 + s * 64 + wv * 16 + lq * 4;
        #pragma unroll
        for (int n = 0; n < 4; ++n)
            #pragma unroll
            for (int r = 0; r < 4; ++r)
                rJ[n * 4 + r] = x[((size_t)(bj0 + r) * F + j) * E + n * 16 + lrow];
    };

    // ---- stage W[p]^T into LDS as bf16, XOR-swizzled (R4 verbatim) ----
    float4 rA0[4], rA1[4];
    float  rJ0[16], rJ1[16];

    issue(0, rA0, rJ0);   // subtile-0 loads overlap W staging

    const float* Wp = W + (size_t)p * E * E;
    #pragma unroll
    for (int it = 0; it < 8; ++it) {
        int q  = tid + it * 256;
        int f  = q & 63;
        int e2 = q >> 6;
        float w0 = Wp[(2 * e2) * E + f];
        float w1 = Wp[(2 * e2 + 1) * E + f];
        unsigned int pk = (unsigned int)f2bf(w0) | ((unsigned int)f2bf(w1) << 16);
        BtU[f * 32 + (e2 ^ ((f & 7) << 2))] = pk;
    }
    __syncthreads();

    const unsigned short* Bts = reinterpret_cast<const unsigned short*>(BtU);

    // B fragments (W^T), register-resident (R4 verbatim)
    s16x8 bfrag[4][2];
    #pragma unroll
    for (int n = 0; n < 4; ++n) {
        int fc = n * 16 + lrow;
        #pragma unroll
        for (int kk = 0; kk < 2; ++kk) {
            int k0 = kk * 32 + lq * 8;
            int sidx = fc * 64 + (k0 ^ ((fc & 7) << 3));
            bfrag[n][kk] = *reinterpret_cast<const s16x8*>(&Bts[sidx]);
        }
    }

    // compute + epilogue for subtile s from the given buffers (R4 verbatim math)
    auto compute = [&](int s, const float4 (&rA)[4], const float (&rJ)[16]) {
        s16x8 xf0 = cvt8(rA[0], rA[1]);
        s16x8 xf1 = cvt8(rA[2], rA[3]);

        f32x4 acc[4];
        #pragma unroll
        for (int n = 0; n < 4; ++n) {
            acc[n] = (f32x4){0.f, 0.f, 0.f, 0.f};
            acc[n] = __builtin_amdgcn_mfma_f32_16x16x32_bf16(xf0, bfrag[n][0], acc[n], 0, 0, 0);
            acc[n] = __builtin_amdgcn_mfma_f32_16x16x32_bf16(xf1, bfrag[n][1], acc[n], 0, 0, 0);
        }

        const int mbase = s * 64 + wv * 16;
        #pragma unroll
        for (int n = 0; n < 4; ++n) {
            int fc = n * 16 + lrow;
            #pragma unroll
            for (int r = 0; r < 4; ++r) {
                int b = b0 + mbase + lq * 4 + r;
                out[((size_t)b * NP + p) * E + fc] = acc[n][r] * rJ[n * 4 + r];
            }
        }
    };

    // software pipeline: loads(s+1) issue BEFORE stores(s) -> waits are
    // vmcnt(16+), stores never drained on the critical path
    issue(1, rA1, rJ1);
    compute(0, rA0, rJ0);
    issue(2, rA0, rJ0);
    compute(1, rA1, rJ1);
    issue(3, rA1, rJ1);
    compute(2, rA0, rJ0);
    compute(3, rA1, rJ1);
}

extern "C" void kernel_launch(void* const* d_in, const int* in_sizes, int n_in,
                              void* d_out, int out_size, void* d_ws, size_t ws_size,
                              hipStream_t stream)
{
    const float* x = (const float*)d_in[0];
    const float* W = (const float*)d_in[1];
    float* out = (float*)d_out;
    dim3 grid(NP * 16, 1, 1);   // 4416 = 8 XCDs x 552
    bilinear_kernel<<<grid, 256, 0, stream>>>(x, W, out);
}

// Round 8
// 73.424 us; speedup vs baseline: 1.5423x; 1.2223x over previous
//
#include <hip/hip_runtime.h>

typedef short s16x8 __attribute__((ext_vector_type(8)));
typedef float f32x4 __attribute__((ext_vector_type(4)));

constexpr int F  = 24;
constexpr int NP = 276;   // F*(F-1)/2
constexpr int E  = 64;

__device__ __forceinline__ unsigned short f2bf(float f) {
    unsigned int u = __builtin_bit_cast(unsigned int, f);
    return (unsigned short)((u + 0x7FFFu + ((u >> 16) & 1u)) >> 16);  // RNE
}

__global__ __launch_bounds__(256)
void bilinear_kernel(const float* __restrict__ x, const float* __restrict__ W,
                     float* __restrict__ out)
{
    __shared__ unsigned int BtU[2048];   // 8 KB: W[p]^T bf16, XOR-swizzled

    // ---- XCD-aware swizzle (T1, as R4) ----
    const int bid = blockIdx.x;
    const int xcd = bid & 7;
    const int idx = bid >> 3;              // 0..551
    const int wl  = (idx >= NP) ? 1 : 0;
    const int p   = idx - wl * NP;
    const int b0  = (xcd * 2 + wl) * 256;

    const int tid = threadIdx.x;
    const int wv  = tid >> 6;
    const int ln  = tid & 63;

    // decode pair (i, j)
    int i = 0, rem = p;
    while (rem >= F - 1 - i) { rem -= F - 1 - i; ++i; }
    const int j = i + 1 + rem;

    // ---- stage W[p]^T into LDS as bf16, byte-XOR swizzled ----
    const float* Wp = W + (size_t)p * E * E;
    #pragma unroll
    for (int it = 0; it < 8; ++it) {
        int q  = tid + it * 256;
        int f  = q & 63;
        int e2 = q >> 6;
        float w0 = Wp[(2 * e2) * E + f];
        float w1 = Wp[(2 * e2 + 1) * E + f];
        unsigned int pk = (unsigned int)f2bf(w0) | ((unsigned int)f2bf(w1) << 16);
        BtU[f * 32 + (e2 ^ ((f & 7) << 2))] = pk;
    }
    __syncthreads();

    const unsigned short* Bts = reinterpret_cast<const unsigned short*>(BtU);

    const int lrow = ln & 15;        // A row / B col / D col within 16
    const int lq   = ln >> 4;        // quarter-wave index

    // B fragments: 4 n-blocks x 2 k-halves, loaded once, reused for all subtiles
    s16x8 bfrag[4][2];
    #pragma unroll
    for (int n = 0; n < 4; ++n) {
        int fc = n * 16 + lrow;
        #pragma unroll
        for (int kk = 0; kk < 2; ++kk) {
            int k0 = kk * 32 + lq * 8;
            int sidx = fc * 64 + (k0 ^ ((fc & 7) << 3));
            bfrag[n][kk] = *reinterpret_cast<const s16x8*>(&Bts[sidx]);
        }
    }

    #pragma unroll 1
    for (int s = 0; s < 4; ++s) {
        const int mbase = s * 64 + wv * 16;

        // A fragments straight from global (L2-hot after swizzle)
        s16x8 afrag[2];
        #pragma unroll
        for (int kk = 0; kk < 2; ++kk) {
            int b  = b0 + mbase + lrow;
            int k0 = kk * 32 + lq * 8;
            const float4* ap = reinterpret_cast<const float4*>(
                x + ((size_t)b * F + i) * E + k0);
            float4 lo = ap[0], hi = ap[1];
            s16x8 a;
            a[0] = (short)f2bf(lo.x); a[1] = (short)f2bf(lo.y);
            a[2] = (short)f2bf(lo.z); a[3] = (short)f2bf(lo.w);
            a[4] = (short)f2bf(hi.x); a[5] = (short)f2bf(hi.y);
            a[6] = (short)f2bf(hi.z); a[7] = (short)f2bf(hi.w);
            afrag[kk] = a;
        }

        f32x4 acc[4];
        #pragma unroll
        for (int n = 0; n < 4; ++n) {
            acc[n] = (f32x4){0.f, 0.f, 0.f, 0.f};
            acc[n] = __builtin_amdgcn_mfma_f32_16x16x32_bf16(afrag[0], bfrag[n][0], acc[n], 0, 0, 0);
            acc[n] = __builtin_amdgcn_mfma_f32_16x16x32_bf16(afrag[1], bfrag[n][1], acc[n], 0, 0, 0);
        }

        // epilogue: D[row=(lq*4+r)][col=lrow]; multiply by xj in fp32,
        // NONTEMPORAL store — out is write-once, keep it out of L2 so the
        // x-slice stays resident (single variable vs R4)
        #pragma unroll
        for (int n = 0; n < 4; ++n) {
            int fc = n * 16 + lrow;
            #pragma unroll
            for (int r = 0; r < 4; ++r) {
                int m = mbase + lq * 4 + r;
                int b = b0 + m;
                float xj = x[((size_t)b * F + j) * E + fc];
                __builtin_nontemporal_store(acc[n][r] * xj,
                    out + ((size_t)b * NP + p) * E + fc);
            }
        }
    }
}

extern "C" void kernel_launch(void* const* d_in, const int* in_sizes, int n_in,
                              void* d_out, int out_size, void* d_ws, size_t ws_size,
                              hipStream_t stream)
{
    const float* x = (const float*)d_in[0];
    const float* W = (const float*)d_in[1];
    float* out = (float*)d_out;
    dim3 grid(NP * 16, 1, 1);   // 4416 = 8 XCDs x 552
    bilinear_kernel<<<grid, 256, 0, stream>>>(x, W, out);
}